// Round 3
// baseline (621.448 us; speedup 1.0000x reference)
//
#include <hip/hip_runtime.h>

#define N_NODES 100000
#define N_EDGES 1600000
#define DIM 64
#define NB1 391           // ceil(N_NODES/256)
#define NGROUPS (N_NODES / 4)   // 25000

// ---------------- workspace layout (int units) ----------------
#define OFF_SOUT    100096
#define OFF_CURSOR  100176
#define OFF_OFFSETS 200272
#define OFF_BSUMS   300416
#define OFF_CSR     300928

// ---------------------------------------------------------------------------
// K1: histogram of dst (4 edges/thread, int4 loads)
// ---------------------------------------------------------------------------
__global__ __launch_bounds__(256) void hist_kernel(
    const int* __restrict__ dst, int* __restrict__ counts)
{
    int e4 = blockIdx.x * 256 + threadIdx.x;
    if (e4 < N_EDGES / 4) {
        int4 d = ((const int4*)dst)[e4];
        atomicAdd(&counts[d.x], 1);
        atomicAdd(&counts[d.y], 1);
        atomicAdd(&counts[d.z], 1);
        atomicAdd(&counts[d.w], 1);
    }
}

// ---------------------------------------------------------------------------
// K2: per-block sums of counts
// ---------------------------------------------------------------------------
__global__ __launch_bounds__(256) void blocksum_kernel(
    const int* __restrict__ counts, int* __restrict__ bsums)
{
    __shared__ int s[256];
    int t = threadIdx.x;
    int idx = blockIdx.x * 256 + t;
    s[t] = (idx < N_NODES) ? counts[idx] : 0;
    __syncthreads();
    for (int d = 128; d > 0; d >>= 1) {
        if (t < d) s[t] += s[t + d];
        __syncthreads();
    }
    if (t == 0) bsums[blockIdx.x] = s[0];
}

// ---------------------------------------------------------------------------
// K3: exclusive scan of the 391 block sums (single block, in place)
// ---------------------------------------------------------------------------
__global__ __launch_bounds__(512) void scanblocks_kernel(int* __restrict__ bsums)
{
    __shared__ int s[512];
    int t = threadIdx.x;
    int v = (t < NB1) ? bsums[t] : 0;
    s[t] = v;
    __syncthreads();
    for (int d = 1; d < 512; d <<= 1) {
        int add = (t >= d) ? s[t - d] : 0;
        __syncthreads();
        s[t] += add;
        __syncthreads();
    }
    if (t < NB1) bsums[t] = (t == 0) ? 0 : s[t - 1];
}

// ---------------------------------------------------------------------------
// K4: per-block exclusive scan + block offset -> offsets[] and cursor[]
// ---------------------------------------------------------------------------
__global__ __launch_bounds__(256) void offsets_kernel(
    const int* __restrict__ counts, const int* __restrict__ bsums,
    int* __restrict__ offsets, int* __restrict__ cursor)
{
    __shared__ int s[256];
    int t = threadIdx.x;
    int idx = blockIdx.x * 256 + t;
    int c = (idx < N_NODES) ? counts[idx] : 0;
    s[t] = c;
    __syncthreads();
    for (int d = 1; d < 256; d <<= 1) {
        int add = (t >= d) ? s[t - d] : 0;
        __syncthreads();
        s[t] += add;
        __syncthreads();
    }
    int excl = (t == 0) ? 0 : s[t - 1];
    int off = bsums[blockIdx.x] + excl;
    if (idx < N_NODES) { offsets[idx] = off; cursor[idx] = off; }
    if (idx == 0) offsets[N_NODES] = N_EDGES;
}

// ---------------------------------------------------------------------------
// K5: scatter edge src indices into CSR slots (4 edges/thread)
// ---------------------------------------------------------------------------
__global__ __launch_bounds__(256) void fill_kernel(
    const int* __restrict__ src, const int* __restrict__ dst,
    int* __restrict__ cursor, int* __restrict__ csr)
{
    int e4 = blockIdx.x * 256 + threadIdx.x;
    if (e4 < N_EDGES / 4) {
        int4 s = ((const int4*)src)[e4];
        int4 d = ((const int4*)dst)[e4];
        int p0 = atomicAdd(&cursor[d.x], 1);
        int p1 = atomicAdd(&cursor[d.y], 1);
        int p2 = atomicAdd(&cursor[d.z], 1);
        int p3 = atomicAdd(&cursor[d.w], 1);
        csr[p0] = s.x;
        csr[p1] = s.y;
        csr[p2] = s.z;
        csr[p3] = s.w;
    }
}

// ---------------------------------------------------------------------------
// K6: fused gather + layer-1 matvec + weighted reduction.
// One wave per 4-node group (grid covers all groups). 4-way unrolled
// edge gather for memory-level parallelism. Lane j owns output column j.
// ---------------------------------------------------------------------------
__global__ __launch_bounds__(256) void gather_mlp_kernel(
    const float* __restrict__ x,
    const int* __restrict__ offsets,
    const int* __restrict__ csr,
    const float* __restrict__ weights,
    const float* __restrict__ W1,
    const float* __restrict__ b1,
    float* __restrict__ sout)
{
    __shared__ float W1s[DIM * DIM];      // 16 KB
    __shared__ float vbuf[4][4][DIM];     // 4 KB
    __shared__ float sred[4][DIM];        // 1 KB

    const int tid  = threadIdx.x;
    const int lane = tid & 63;
    const int wave = tid >> 6;

    for (int i = tid; i < DIM * DIM; i += 256) W1s[i] = W1[i];
    __syncthreads();

    const float bias = b1[lane];
    float sacc  = 0.f;
    float swacc = 0.f;

    const int g = blockIdx.x * 4 + wave;   // one group per wave

    if (g < NGROUPS) {
        const int i0 = g * 4;
        #pragma unroll
        for (int n = 0; n < 4; ++n) {
            const int node = i0 + n;
            const int beg = __builtin_amdgcn_readfirstlane(offsets[node]);
            const int end = __builtin_amdgcn_readfirstlane(offsets[node + 1]);
            float a0 = x[(size_t)node * DIM + lane];   // self term (eps=0)
            float a1 = 0.f, a2 = 0.f, a3 = 0.f;
            int j = beg;
            for (; j + 4 <= end; j += 4) {
                const int s0 = csr[j + 0];
                const int s1 = csr[j + 1];
                const int s2 = csr[j + 2];
                const int s3 = csr[j + 3];
                a0 += x[(size_t)s0 * DIM + lane];
                a1 += x[(size_t)s1 * DIM + lane];
                a2 += x[(size_t)s2 * DIM + lane];
                a3 += x[(size_t)s3 * DIM + lane];
            }
            for (; j < end; ++j)
                a1 += x[(size_t)csr[j] * DIM + lane];
            vbuf[wave][n][lane] = (a0 + a1) + (a2 + a3);
        }

        float a0 = bias, a1 = bias, a2 = bias, a3 = bias;
        #pragma unroll
        for (int k = 0; k < DIM; k += 4) {
            float4 q0 = *(const float4*)&vbuf[wave][0][k];
            float4 q1 = *(const float4*)&vbuf[wave][1][k];
            float4 q2 = *(const float4*)&vbuf[wave][2][k];
            float4 q3 = *(const float4*)&vbuf[wave][3][k];
            float w0 = W1s[(k + 0) * DIM + lane];
            float w1 = W1s[(k + 1) * DIM + lane];
            float w2 = W1s[(k + 2) * DIM + lane];
            float w3 = W1s[(k + 3) * DIM + lane];
            a0 = fmaf(q0.x, w0, a0); a0 = fmaf(q0.y, w1, a0);
            a0 = fmaf(q0.z, w2, a0); a0 = fmaf(q0.w, w3, a0);
            a1 = fmaf(q1.x, w0, a1); a1 = fmaf(q1.y, w1, a1);
            a1 = fmaf(q1.z, w2, a1); a1 = fmaf(q1.w, w3, a1);
            a2 = fmaf(q2.x, w0, a2); a2 = fmaf(q2.y, w1, a2);
            a2 = fmaf(q2.z, w2, a2); a2 = fmaf(q2.w, w3, a2);
            a3 = fmaf(q3.x, w0, a3); a3 = fmaf(q3.y, w1, a3);
            a3 = fmaf(q3.z, w2, a3); a3 = fmaf(q3.w, w3, a3);
        }

        const float wt0 = weights[i0 + 0];
        const float wt1 = weights[i0 + 1];
        const float wt2 = weights[i0 + 2];
        const float wt3 = weights[i0 + 3];
        sacc = fmaf(fmaxf(a0, 0.f), wt0, sacc);
        sacc = fmaf(fmaxf(a1, 0.f), wt1, sacc);
        sacc = fmaf(fmaxf(a2, 0.f), wt2, sacc);
        sacc = fmaf(fmaxf(a3, 0.f), wt3, sacc);
        if (lane == 0) swacc += wt0 + wt1 + wt2 + wt3;
    }

    sred[wave][lane] = sacc;
    __syncthreads();
    if (wave == 0) {
        float t = sred[0][lane] + sred[1][lane] + sred[2][lane] + sred[3][lane];
        atomicAdd(&sout[lane], t);
    }
    if (lane == 0) atomicAdd(&sout[DIM], swacc);
}

// ---------------------------------------------------------------------------
// K7: out = s @ W2 + sw * b2
// ---------------------------------------------------------------------------
__global__ void finalize_kernel(
    const float* __restrict__ sout,
    const float* __restrict__ W2,
    const float* __restrict__ b2,
    float* __restrict__ out)
{
    const int j = threadIdx.x;
    const float sw = sout[DIM];
    float acc = sw * b2[j];
    #pragma unroll
    for (int k = 0; k < DIM; ++k)
        acc = fmaf(sout[k], W2[k * DIM + j], acc);
    out[j] = acc;
}

extern "C" void kernel_launch(void* const* d_in, const int* in_sizes, int n_in,
                              void* d_out, int out_size, void* d_ws, size_t ws_size,
                              hipStream_t stream)
{
    const float* x       = (const float*)d_in[0];
    const int*   ei      = (const int*)d_in[1];
    const float* weights = (const float*)d_in[2];
    const float* W1      = (const float*)d_in[3];
    const float* b1      = (const float*)d_in[4];
    const float* W2      = (const float*)d_in[5];
    const float* b2      = (const float*)d_in[6];
    float* out = (float*)d_out;

    const int* src = ei;
    const int* dst = ei + N_EDGES;

    int*   wsI     = (int*)d_ws;
    int*   counts  = wsI;
    float* soutF   = (float*)(wsI + OFF_SOUT);
    int*   cursor  = wsI + OFF_CURSOR;
    int*   offsets = wsI + OFF_OFFSETS;
    int*   bsums   = wsI + OFF_BSUMS;
    int*   csr     = wsI + OFF_CSR;

    hipMemsetAsync(d_ws, 0, (size_t)(OFF_SOUT + 80) * sizeof(int), stream);

    const int e4blk = (N_EDGES / 4 + 255) / 256;   // 1563
    hist_kernel      <<<e4blk, 256, 0, stream>>>(dst, counts);
    blocksum_kernel  <<<NB1,   256, 0, stream>>>(counts, bsums);
    scanblocks_kernel<<<1,     512, 0, stream>>>(bsums);
    offsets_kernel   <<<NB1,   256, 0, stream>>>(counts, bsums, offsets, cursor);
    fill_kernel      <<<e4blk, 256, 0, stream>>>(src, dst, cursor, csr);
    gather_mlp_kernel<<<(NGROUPS + 3) / 4, 256, 0, stream>>>(x, offsets, csr, weights, W1, b1, soutF);
    finalize_kernel  <<<1,      64, 0, stream>>>(soutF, W2, b2, out);
}

// Round 4
// 432.598 us; speedup vs baseline: 1.4365x; 1.4365x over previous
//
#include <hip/hip_runtime.h>
#include <hip/hip_bf16.h>

#define N_NODES 100000
#define N_EDGES 1600000
#define DIM 64
#define NB1 391                 // ceil(N_NODES/256)
#define NGROUPS (N_NODES / 4)   // 25000
#define NBLK_GM 1792            // 7 blocks/CU * 256 CU

// ---------------- workspace layout (int units) ----------------
#define OFF_SOUT    100096
#define OFF_CURSOR  100176
#define OFF_OFFSETS 200272
#define OFF_BSUMS   300416
#define OFF_CSR     300928
#define OFF_Y16     1900928     // bf16 x copy: N_NODES*DIM ushorts = 3.2M ints

__device__ __forceinline__ float blo(unsigned u) { return __uint_as_float(u << 16); }
__device__ __forceinline__ float bhi(unsigned u) { return __uint_as_float(u & 0xffff0000u); }

// ---------------------------------------------------------------------------
// K0: convert x rows to bf16 (packed, row = 64 bf16 = 128 B)
// ---------------------------------------------------------------------------
__global__ __launch_bounds__(256) void convert_kernel(
    const float* __restrict__ x, unsigned* __restrict__ y)
{
    int i = blockIdx.x * 256 + threadIdx.x;       // over N*64/4 = 1.6M float4
    if (i < N_NODES * DIM / 4) {
        float4 v = ((const float4*)x)[i];
        __hip_bfloat162 p0 = __float22bfloat162_rn(make_float2(v.x, v.y));
        __hip_bfloat162 p1 = __float22bfloat162_rn(make_float2(v.z, v.w));
        uint2 o;
        o.x = *reinterpret_cast<unsigned*>(&p0);
        o.y = *reinterpret_cast<unsigned*>(&p1);
        ((uint2*)y)[i] = o;
    }
}

// ---------------------------------------------------------------------------
// K1: histogram of dst (4 edges/thread)
// ---------------------------------------------------------------------------
__global__ __launch_bounds__(256) void hist_kernel(
    const int* __restrict__ dst, int* __restrict__ counts)
{
    int e4 = blockIdx.x * 256 + threadIdx.x;
    if (e4 < N_EDGES / 4) {
        int4 d = ((const int4*)dst)[e4];
        atomicAdd(&counts[d.x], 1);
        atomicAdd(&counts[d.y], 1);
        atomicAdd(&counts[d.z], 1);
        atomicAdd(&counts[d.w], 1);
    }
}

// ---------------------------------------------------------------------------
// K2/K3/K4: scan pipeline -> offsets[] and cursor[]
// ---------------------------------------------------------------------------
__global__ __launch_bounds__(256) void blocksum_kernel(
    const int* __restrict__ counts, int* __restrict__ bsums)
{
    __shared__ int s[256];
    int t = threadIdx.x;
    int idx = blockIdx.x * 256 + t;
    s[t] = (idx < N_NODES) ? counts[idx] : 0;
    __syncthreads();
    for (int d = 128; d > 0; d >>= 1) {
        if (t < d) s[t] += s[t + d];
        __syncthreads();
    }
    if (t == 0) bsums[blockIdx.x] = s[0];
}

__global__ __launch_bounds__(512) void scanblocks_kernel(int* __restrict__ bsums)
{
    __shared__ int s[512];
    int t = threadIdx.x;
    int v = (t < NB1) ? bsums[t] : 0;
    s[t] = v;
    __syncthreads();
    for (int d = 1; d < 512; d <<= 1) {
        int add = (t >= d) ? s[t - d] : 0;
        __syncthreads();
        s[t] += add;
        __syncthreads();
    }
    if (t < NB1) bsums[t] = (t == 0) ? 0 : s[t - 1];
}

__global__ __launch_bounds__(256) void offsets_kernel(
    const int* __restrict__ counts, const int* __restrict__ bsums,
    int* __restrict__ offsets, int* __restrict__ cursor)
{
    __shared__ int s[256];
    int t = threadIdx.x;
    int idx = blockIdx.x * 256 + t;
    int c = (idx < N_NODES) ? counts[idx] : 0;
    s[t] = c;
    __syncthreads();
    for (int d = 1; d < 256; d <<= 1) {
        int add = (t >= d) ? s[t - d] : 0;
        __syncthreads();
        s[t] += add;
        __syncthreads();
    }
    int excl = (t == 0) ? 0 : s[t - 1];
    int off = bsums[blockIdx.x] + excl;
    if (idx < N_NODES) { offsets[idx] = off; cursor[idx] = off; }
    if (idx == 0) offsets[N_NODES] = N_EDGES;
}

// ---------------------------------------------------------------------------
// K5: scatter edge src indices into CSR slots
// ---------------------------------------------------------------------------
__global__ __launch_bounds__(256) void fill_kernel(
    const int* __restrict__ src, const int* __restrict__ dst,
    int* __restrict__ cursor, int* __restrict__ csr)
{
    int e4 = blockIdx.x * 256 + threadIdx.x;
    if (e4 < N_EDGES / 4) {
        int4 s = ((const int4*)src)[e4];
        int4 d = ((const int4*)dst)[e4];
        int p0 = atomicAdd(&cursor[d.x], 1);
        int p1 = atomicAdd(&cursor[d.y], 1);
        int p2 = atomicAdd(&cursor[d.z], 1);
        int p3 = atomicAdd(&cursor[d.w], 1);
        csr[p0] = s.x;
        csr[p1] = s.y;
        csr[p2] = s.z;
        csr[p3] = s.w;
    }
}

// ---------------------------------------------------------------------------
// K6: fused bf16 gather (8 edges / 1KB instruction) + layer-1 matvec +
// weighted reduction. Persistent blocks, one wave per 4-node group per iter.
// Lane = 8*slot + h: loads uint4 (cols 8h..8h+7) of edge-slot; butterfly
// shfl_xor(8/16/32) reduces slots. Self term added in fp32.
// ---------------------------------------------------------------------------
__global__ __launch_bounds__(256) void gather_mlp_kernel(
    const float* __restrict__ x,
    const unsigned* __restrict__ y16,
    const int* __restrict__ offsets,
    const int* __restrict__ csr,
    const float* __restrict__ weights,
    const float* __restrict__ W1,
    const float* __restrict__ b1,
    float* __restrict__ sout)
{
    __shared__ float W1s[DIM * DIM];      // 16 KB
    __shared__ float vbuf[4][4][DIM];     // 4 KB
    __shared__ float sred[4][DIM];        // 1 KB

    const int tid  = threadIdx.x;
    const int lane = tid & 63;
    const int wave = tid >> 6;
    const int slot = lane >> 3;           // edge sub-slot 0..7
    const int h    = lane & 7;            // column octet 0..7

    for (int i = tid; i < DIM * DIM; i += 256) W1s[i] = W1[i];
    __syncthreads();

    const float bias = b1[lane];
    float sacc  = 0.f;
    float swacc = 0.f;

    const uint4* yrows = (const uint4*)y16;   // 8 uint4 per row

    for (int g = blockIdx.x * 4 + wave; g < NGROUPS; g += NBLK_GM * 4) {
        const int i0 = g * 4;

        #pragma unroll
        for (int n = 0; n < 4; ++n) {
            const int node = i0 + n;
            const int beg = __builtin_amdgcn_readfirstlane(offsets[node]);
            const int end = __builtin_amdgcn_readfirstlane(offsets[node + 1]);
            const int d = end - beg;

            if (d <= 64) {
                // lane-parallel index fetch: one coalesced load for the node
                int myidx = 0;
                if (lane < d) myidx = csr[beg + lane];

                float a0 = 0.f, a1 = 0.f, a2 = 0.f, a3 = 0.f;
                float a4 = 0.f, a5 = 0.f, a6 = 0.f, a7 = 0.f;
                const int nchunks = (d + 7) >> 3;
                int c = 0;
                for (; c + 2 <= nchunks; c += 2) {
                    const int e0 = c * 8 + slot;      // e0 < d always here
                    const int e1 = e0 + 8;
                    const int s0 = __shfl(myidx, e0);
                    const int s1 = __shfl(myidx, e1);
                    uint4 r0 = yrows[(size_t)s0 * 8 + h];
                    a0 += blo(r0.x); a1 += bhi(r0.x);
                    a2 += blo(r0.y); a3 += bhi(r0.y);
                    a4 += blo(r0.z); a5 += bhi(r0.z);
                    a6 += blo(r0.w); a7 += bhi(r0.w);
                    if (e1 < d) {
                        uint4 r1 = yrows[(size_t)s1 * 8 + h];
                        a0 += blo(r1.x); a1 += bhi(r1.x);
                        a2 += blo(r1.y); a3 += bhi(r1.y);
                        a4 += blo(r1.z); a5 += bhi(r1.z);
                        a6 += blo(r1.w); a7 += bhi(r1.w);
                    }
                }
                if (c < nchunks) {
                    const int e0 = c * 8 + slot;
                    const int s0 = __shfl(myidx, e0);
                    if (e0 < d) {
                        uint4 r0 = yrows[(size_t)s0 * 8 + h];
                        a0 += blo(r0.x); a1 += bhi(r0.x);
                        a2 += blo(r0.y); a3 += bhi(r0.y);
                        a4 += blo(r0.z); a5 += bhi(r0.z);
                        a6 += blo(r0.w); a7 += bhi(r0.w);
                    }
                }
                // butterfly over edge-slot bits (3,4,5): every lane ends with
                // the column-octet h totals
                #pragma unroll
                for (int m = 8; m <= 32; m <<= 1) {
                    a0 += __shfl_xor(a0, m); a1 += __shfl_xor(a1, m);
                    a2 += __shfl_xor(a2, m); a3 += __shfl_xor(a3, m);
                    a4 += __shfl_xor(a4, m); a5 += __shfl_xor(a5, m);
                    a6 += __shfl_xor(a6, m); a7 += __shfl_xor(a7, m);
                }
                if (lane < 8) {
                    *(float4*)&vbuf[wave][n][lane * 8]     = make_float4(a0, a1, a2, a3);
                    *(float4*)&vbuf[wave][n][lane * 8 + 4] = make_float4(a4, a5, a6, a7);
                }
            } else {
                // ultra-rare fallback (deg > 64): per-lane fp32 gather
                float aa = 0.f;
                for (int j = beg; j < end; ++j)
                    aa += x[(size_t)csr[j] * DIM + lane];
                vbuf[wave][n][lane] = aa;
            }
            // self term in fp32 (same-wave LDS RMW; compiler orders via lgkmcnt)
            const float selfv = x[(size_t)node * DIM + lane];
            vbuf[wave][n][lane] += selfv;
        }

        float a0 = bias, a1 = bias, a2 = bias, a3 = bias;
        #pragma unroll
        for (int k = 0; k < DIM; k += 4) {
            float4 q0 = *(const float4*)&vbuf[wave][0][k];
            float4 q1 = *(const float4*)&vbuf[wave][1][k];
            float4 q2 = *(const float4*)&vbuf[wave][2][k];
            float4 q3 = *(const float4*)&vbuf[wave][3][k];
            float w0 = W1s[(k + 0) * DIM + lane];
            float w1 = W1s[(k + 1) * DIM + lane];
            float w2 = W1s[(k + 2) * DIM + lane];
            float w3 = W1s[(k + 3) * DIM + lane];
            a0 = fmaf(q0.x, w0, a0); a0 = fmaf(q0.y, w1, a0);
            a0 = fmaf(q0.z, w2, a0); a0 = fmaf(q0.w, w3, a0);
            a1 = fmaf(q1.x, w0, a1); a1 = fmaf(q1.y, w1, a1);
            a1 = fmaf(q1.z, w2, a1); a1 = fmaf(q1.w, w3, a1);
            a2 = fmaf(q2.x, w0, a2); a2 = fmaf(q2.y, w1, a2);
            a2 = fmaf(q2.z, w2, a2); a2 = fmaf(q2.w, w3, a2);
            a3 = fmaf(q3.x, w0, a3); a3 = fmaf(q3.y, w1, a3);
            a3 = fmaf(q3.z, w2, a3); a3 = fmaf(q3.w, w3, a3);
        }

        const float wt0 = weights[i0 + 0];
        const float wt1 = weights[i0 + 1];
        const float wt2 = weights[i0 + 2];
        const float wt3 = weights[i0 + 3];
        sacc = fmaf(fmaxf(a0, 0.f), wt0, sacc);
        sacc = fmaf(fmaxf(a1, 0.f), wt1, sacc);
        sacc = fmaf(fmaxf(a2, 0.f), wt2, sacc);
        sacc = fmaf(fmaxf(a3, 0.f), wt3, sacc);
        if (lane == 0) swacc += wt0 + wt1 + wt2 + wt3;
    }

    sred[wave][lane] = sacc;
    __syncthreads();
    if (wave == 0) {
        float t = sred[0][lane] + sred[1][lane] + sred[2][lane] + sred[3][lane];
        atomicAdd(&sout[lane], t);
    }
    if (lane == 0) atomicAdd(&sout[DIM], swacc);
}

// ---------------------------------------------------------------------------
// K7: out = s @ W2 + sw * b2
// ---------------------------------------------------------------------------
__global__ void finalize_kernel(
    const float* __restrict__ sout,
    const float* __restrict__ W2,
    const float* __restrict__ b2,
    float* __restrict__ out)
{
    const int j = threadIdx.x;
    const float sw = sout[DIM];
    float acc = sw * b2[j];
    #pragma unroll
    for (int k = 0; k < DIM; ++k)
        acc = fmaf(sout[k], W2[k * DIM + j], acc);
    out[j] = acc;
}

extern "C" void kernel_launch(void* const* d_in, const int* in_sizes, int n_in,
                              void* d_out, int out_size, void* d_ws, size_t ws_size,
                              hipStream_t stream)
{
    const float* x       = (const float*)d_in[0];
    const int*   ei      = (const int*)d_in[1];
    const float* weights = (const float*)d_in[2];
    const float* W1      = (const float*)d_in[3];
    const float* b1      = (const float*)d_in[4];
    const float* W2      = (const float*)d_in[5];
    const float* b2      = (const float*)d_in[6];
    float* out = (float*)d_out;

    const int* src = ei;
    const int* dst = ei + N_EDGES;

    int*      wsI     = (int*)d_ws;
    int*      counts  = wsI;
    float*    soutF   = (float*)(wsI + OFF_SOUT);
    int*      cursor  = wsI + OFF_CURSOR;
    int*      offsets = wsI + OFF_OFFSETS;
    int*      bsums   = wsI + OFF_BSUMS;
    int*      csr     = wsI + OFF_CSR;
    unsigned* y16     = (unsigned*)(wsI + OFF_Y16);

    hipMemsetAsync(d_ws, 0, (size_t)(OFF_SOUT + 80) * sizeof(int), stream);

    const int e4blk = (N_EDGES / 4 + 255) / 256;   // 1563
    convert_kernel   <<<(N_NODES * DIM / 4 + 255) / 256, 256, 0, stream>>>(x, y16);
    hist_kernel      <<<e4blk, 256, 0, stream>>>(dst, counts);
    blocksum_kernel  <<<NB1,   256, 0, stream>>>(counts, bsums);
    scanblocks_kernel<<<1,     512, 0, stream>>>(bsums);
    offsets_kernel   <<<NB1,   256, 0, stream>>>(counts, bsums, offsets, cursor);
    fill_kernel      <<<e4blk, 256, 0, stream>>>(src, dst, cursor, csr);
    gather_mlp_kernel<<<NBLK_GM, 256, 0, stream>>>(x, y16, offsets, csr, weights, W1, b1, soutF);
    finalize_kernel  <<<1,      64, 0, stream>>>(soutF, W2, b2, out);
}

// Round 5
// 393.010 us; speedup vs baseline: 1.5813x; 1.1007x over previous
//
#include <hip/hip_runtime.h>
#include <hip/hip_bf16.h>

#define N_NODES 100000
#define N_EDGES 1600000
#define DIM 64
#define NB1 391                 // ceil(N_NODES/256)
#define NGROUPS (N_NODES / 4)   // 25000
#define NBLK_GM 1536            // ~6 blocks/CU * 256 CU (persistent)

// ---------------- workspace layout (int units) ----------------
#define OFF_SOUT    100096
#define OFF_CURSOR  100176
#define OFF_OFFSETS 200272
#define OFF_BSUMS   300416
#define OFF_CSR     300928
#define OFF_Y16     1900928     // bf16 x copy: N_NODES*DIM ushorts

__device__ __forceinline__ float blo(unsigned u) { return __uint_as_float(u << 16); }
__device__ __forceinline__ float bhi(unsigned u) { return __uint_as_float(u & 0xffff0000u); }

// ---------------------------------------------------------------------------
// K0: fused convert(x->bf16) + histogram of dst (independent work, one launch)
// ---------------------------------------------------------------------------
__global__ __launch_bounds__(256) void convert_hist_kernel(
    const float* __restrict__ x, unsigned* __restrict__ y,
    const int* __restrict__ dst, int* __restrict__ counts)
{
    int i = blockIdx.x * 256 + threadIdx.x;
    if (i < N_NODES * DIM / 4) {
        float4 v = ((const float4*)x)[i];
        __hip_bfloat162 p0 = __float22bfloat162_rn(make_float2(v.x, v.y));
        __hip_bfloat162 p1 = __float22bfloat162_rn(make_float2(v.z, v.w));
        uint2 o;
        o.x = *reinterpret_cast<unsigned*>(&p0);
        o.y = *reinterpret_cast<unsigned*>(&p1);
        ((uint2*)y)[i] = o;
    }
    if (i < N_EDGES / 4) {
        int4 d = ((const int4*)dst)[i];
        atomicAdd(&counts[d.x], 1);
        atomicAdd(&counts[d.y], 1);
        atomicAdd(&counts[d.z], 1);
        atomicAdd(&counts[d.w], 1);
    }
}

// ---------------------------------------------------------------------------
// K2/K3/K4: scan pipeline -> offsets[] and cursor[]
// ---------------------------------------------------------------------------
__global__ __launch_bounds__(256) void blocksum_kernel(
    const int* __restrict__ counts, int* __restrict__ bsums)
{
    __shared__ int s[256];
    int t = threadIdx.x;
    int idx = blockIdx.x * 256 + t;
    s[t] = (idx < N_NODES) ? counts[idx] : 0;
    __syncthreads();
    for (int d = 128; d > 0; d >>= 1) {
        if (t < d) s[t] += s[t + d];
        __syncthreads();
    }
    if (t == 0) bsums[blockIdx.x] = s[0];
}

__global__ __launch_bounds__(512) void scanblocks_kernel(int* __restrict__ bsums)
{
    __shared__ int s[512];
    int t = threadIdx.x;
    int v = (t < NB1) ? bsums[t] : 0;
    s[t] = v;
    __syncthreads();
    for (int d = 1; d < 512; d <<= 1) {
        int add = (t >= d) ? s[t - d] : 0;
        __syncthreads();
        s[t] += add;
        __syncthreads();
    }
    if (t < NB1) bsums[t] = (t == 0) ? 0 : s[t - 1];
}

__global__ __launch_bounds__(256) void offsets_kernel(
    const int* __restrict__ counts, const int* __restrict__ bsums,
    int* __restrict__ offsets, int* __restrict__ cursor)
{
    __shared__ int s[256];
    int t = threadIdx.x;
    int idx = blockIdx.x * 256 + t;
    int c = (idx < N_NODES) ? counts[idx] : 0;
    s[t] = c;
    __syncthreads();
    for (int d = 1; d < 256; d <<= 1) {
        int add = (t >= d) ? s[t - d] : 0;
        __syncthreads();
        s[t] += add;
        __syncthreads();
    }
    int excl = (t == 0) ? 0 : s[t - 1];
    int off = bsums[blockIdx.x] + excl;
    if (idx < N_NODES) { offsets[idx] = off; cursor[idx] = off; }
    if (idx == 0) offsets[N_NODES] = N_EDGES;
}

// ---------------------------------------------------------------------------
// K5: scatter edge src indices into CSR slots
// ---------------------------------------------------------------------------
__global__ __launch_bounds__(256) void fill_kernel(
    const int* __restrict__ src, const int* __restrict__ dst,
    int* __restrict__ cursor, int* __restrict__ csr)
{
    int e4 = blockIdx.x * 256 + threadIdx.x;
    if (e4 < N_EDGES / 4) {
        int4 s = ((const int4*)src)[e4];
        int4 d = ((const int4*)dst)[e4];
        int p0 = atomicAdd(&cursor[d.x], 1);
        int p1 = atomicAdd(&cursor[d.y], 1);
        int p2 = atomicAdd(&cursor[d.z], 1);
        int p3 = atomicAdd(&cursor[d.w], 1);
        csr[p0] = s.x;
        csr[p1] = s.y;
        csr[p2] = s.z;
        csr[p3] = s.w;
    }
}

// ---------------------------------------------------------------------------
// K6: fused bf16 gather + layer-1 matvec + weighted reduction.
// Phase-interleaved: all index loads, then all row loads (4 nodes x 3 chunks),
// then unpack/butterfly. ~12 loads in flight per wave.
// ---------------------------------------------------------------------------
__global__ __launch_bounds__(256) void gather_mlp_kernel(
    const float* __restrict__ x,
    const unsigned* __restrict__ y16,
    const int* __restrict__ offsets,
    const int* __restrict__ csr,
    const float* __restrict__ weights,
    const float* __restrict__ W1,
    const float* __restrict__ b1,
    float* __restrict__ sout)
{
    __shared__ float W1s[DIM * DIM];      // 16 KB
    __shared__ float vbuf[4][4][DIM];     // 4 KB
    __shared__ float sred[4][DIM];        // 1 KB

    const int tid  = threadIdx.x;
    const int lane = tid & 63;
    const int wave = tid >> 6;
    const int slot = lane >> 3;           // edge sub-slot 0..7
    const int h    = lane & 7;            // column octet 0..7

    for (int i = tid; i < DIM * DIM; i += 256) W1s[i] = W1[i];
    __syncthreads();

    const float bias = b1[lane];
    float sacc  = 0.f;
    float swacc = 0.f;

    const uint4* yrows = (const uint4*)y16;   // 8 uint4 per row

    for (int g = blockIdx.x * 4 + wave; g < NGROUPS; g += NBLK_GM * 4) {
        const int i0 = g * 4;

        // --- offsets for the 4 nodes in ONE lane-parallel load ---
        int off_l = offsets[i0 + (lane < 5 ? lane : 4)];
        int bg[4], dd[4];
        #pragma unroll
        for (int n = 0; n < 4; ++n) {
            int b = __builtin_amdgcn_readfirstlane(__shfl(off_l, n));
            int e = __builtin_amdgcn_readfirstlane(__shfl(off_l, n + 1));
            bg[n] = b; dd[n] = e - b;
        }

        // --- Phase A: index loads + self terms (8 independent loads) ---
        int idx[4];
        float selfv[4];
        #pragma unroll
        for (int n = 0; n < 4; ++n)
            idx[n] = (lane < dd[n]) ? csr[bg[n] + lane] : 0;
        #pragma unroll
        for (int n = 0; n < 4; ++n)
            selfv[n] = x[(size_t)(i0 + n) * DIM + lane];

        // --- Phase B: row loads, 4 nodes x up to 3 chunks ---
        uint4 r[4][3];
        #pragma unroll
        for (int n = 0; n < 4; ++n) {
            #pragma unroll
            for (int c = 0; c < 3; ++c) {
                r[n][c] = make_uint4(0u, 0u, 0u, 0u);
                if (c * 8 < dd[n]) {                    // wave-uniform branch
                    const int e = c * 8 + slot;         // < 24, valid shfl idx
                    const int s = __shfl(idx[n], e);    // 0 for tail lanes
                    uint4 rr = yrows[(size_t)s * 8 + h];
                    if (e < dd[n]) r[n][c] = rr;        // cndmask tail -> 0
                }
            }
        }

        // --- Phase C: unpack + remainder + butterfly + store ---
        #pragma unroll
        for (int n = 0; n < 4; ++n) {
            float a0 = 0.f, a1 = 0.f, a2 = 0.f, a3 = 0.f;
            float a4 = 0.f, a5 = 0.f, a6 = 0.f, a7 = 0.f;
            #pragma unroll
            for (int c = 0; c < 3; ++c) {
                uint4 rr = r[n][c];
                a0 += blo(rr.x); a1 += bhi(rr.x);
                a2 += blo(rr.y); a3 += bhi(rr.y);
                a4 += blo(rr.z); a5 += bhi(rr.z);
                a6 += blo(rr.w); a7 += bhi(rr.w);
            }
            if (dd[n] > 24) {
                const int dcap = dd[n] <= 64 ? dd[n] : 64;
                for (int c = 3; c * 8 < dcap; ++c) {     // uniform branch
                    const int e = c * 8 + slot;
                    const int s = __shfl(idx[n], e < 64 ? e : 0);
                    if (e < dcap) {
                        uint4 rr = yrows[(size_t)s * 8 + h];
                        a0 += blo(rr.x); a1 += bhi(rr.x);
                        a2 += blo(rr.y); a3 += bhi(rr.y);
                        a4 += blo(rr.z); a5 += bhi(rr.z);
                        a6 += blo(rr.w); a7 += bhi(rr.w);
                    }
                }
                if (dd[n] > 64) {                        // essentially never
                    for (int jj = bg[n] + 64; jj < bg[n] + dd[n]; ++jj) {
                        const int s = csr[jj];
                        if (slot == 0) {
                            uint4 rr = yrows[(size_t)s * 8 + h];
                            a0 += blo(rr.x); a1 += bhi(rr.x);
                            a2 += blo(rr.y); a3 += bhi(rr.y);
                            a4 += blo(rr.z); a5 += bhi(rr.z);
                            a6 += blo(rr.w); a7 += bhi(rr.w);
                        }
                    }
                }
            }
            #pragma unroll
            for (int m = 8; m <= 32; m <<= 1) {
                a0 += __shfl_xor(a0, m); a1 += __shfl_xor(a1, m);
                a2 += __shfl_xor(a2, m); a3 += __shfl_xor(a3, m);
                a4 += __shfl_xor(a4, m); a5 += __shfl_xor(a5, m);
                a6 += __shfl_xor(a6, m); a7 += __shfl_xor(a7, m);
            }
            if (lane < 8) {
                *(float4*)&vbuf[wave][n][lane * 8]     = make_float4(a0, a1, a2, a3);
                *(float4*)&vbuf[wave][n][lane * 8 + 4] = make_float4(a4, a5, a6, a7);
            }
            vbuf[wave][n][lane] += selfv[n];   // same-wave LDS RMW, in-order
        }

        // --- MLP layer 1 + weighted accumulation ---
        float a0 = bias, a1 = bias, a2 = bias, a3 = bias;
        #pragma unroll
        for (int k = 0; k < DIM; k += 4) {
            float4 q0 = *(const float4*)&vbuf[wave][0][k];
            float4 q1 = *(const float4*)&vbuf[wave][1][k];
            float4 q2 = *(const float4*)&vbuf[wave][2][k];
            float4 q3 = *(const float4*)&vbuf[wave][3][k];
            float w0 = W1s[(k + 0) * DIM + lane];
            float w1 = W1s[(k + 1) * DIM + lane];
            float w2 = W1s[(k + 2) * DIM + lane];
            float w3 = W1s[(k + 3) * DIM + lane];
            a0 = fmaf(q0.x, w0, a0); a0 = fmaf(q0.y, w1, a0);
            a0 = fmaf(q0.z, w2, a0); a0 = fmaf(q0.w, w3, a0);
            a1 = fmaf(q1.x, w0, a1); a1 = fmaf(q1.y, w1, a1);
            a1 = fmaf(q1.z, w2, a1); a1 = fmaf(q1.w, w3, a1);
            a2 = fmaf(q2.x, w0, a2); a2 = fmaf(q2.y, w1, a2);
            a2 = fmaf(q2.z, w2, a2); a2 = fmaf(q2.w, w3, a2);
            a3 = fmaf(q3.x, w0, a3); a3 = fmaf(q3.y, w1, a3);
            a3 = fmaf(q3.z, w2, a3); a3 = fmaf(q3.w, w3, a3);
        }

        const float wt0 = weights[i0 + 0];
        const float wt1 = weights[i0 + 1];
        const float wt2 = weights[i0 + 2];
        const float wt3 = weights[i0 + 3];
        sacc = fmaf(fmaxf(a0, 0.f), wt0, sacc);
        sacc = fmaf(fmaxf(a1, 0.f), wt1, sacc);
        sacc = fmaf(fmaxf(a2, 0.f), wt2, sacc);
        sacc = fmaf(fmaxf(a3, 0.f), wt3, sacc);
        if (lane == 0) swacc += wt0 + wt1 + wt2 + wt3;
    }

    sred[wave][lane] = sacc;
    __syncthreads();
    if (wave == 0) {
        float t = sred[0][lane] + sred[1][lane] + sred[2][lane] + sred[3][lane];
        atomicAdd(&sout[lane], t);
    }
    if (lane == 0) atomicAdd(&sout[DIM], swacc);
}

// ---------------------------------------------------------------------------
// K7: out = s @ W2 + sw * b2
// ---------------------------------------------------------------------------
__global__ void finalize_kernel(
    const float* __restrict__ sout,
    const float* __restrict__ W2,
    const float* __restrict__ b2,
    float* __restrict__ out)
{
    const int j = threadIdx.x;
    const float sw = sout[DIM];
    float acc = sw * b2[j];
    #pragma unroll
    for (int k = 0; k < DIM; ++k)
        acc = fmaf(sout[k], W2[k * DIM + j], acc);
    out[j] = acc;
}

extern "C" void kernel_launch(void* const* d_in, const int* in_sizes, int n_in,
                              void* d_out, int out_size, void* d_ws, size_t ws_size,
                              hipStream_t stream)
{
    const float* x       = (const float*)d_in[0];
    const int*   ei      = (const int*)d_in[1];
    const float* weights = (const float*)d_in[2];
    const float* W1      = (const float*)d_in[3];
    const float* b1      = (const float*)d_in[4];
    const float* W2      = (const float*)d_in[5];
    const float* b2      = (const float*)d_in[6];
    float* out = (float*)d_out;

    const int* src = ei;
    const int* dst = ei + N_EDGES;

    int*      wsI     = (int*)d_ws;
    int*      counts  = wsI;
    float*    soutF   = (float*)(wsI + OFF_SOUT);
    int*      cursor  = wsI + OFF_CURSOR;
    int*      offsets = wsI + OFF_OFFSETS;
    int*      bsums   = wsI + OFF_BSUMS;
    int*      csr     = wsI + OFF_CSR;
    unsigned* y16     = (unsigned*)(wsI + OFF_Y16);

    hipMemsetAsync(d_ws, 0, (size_t)(OFF_SOUT + 80) * sizeof(int), stream);

    const int e4blk = (N_EDGES / 4 + 255) / 256;   // 1563
    convert_hist_kernel<<<(N_NODES * DIM / 4 + 255) / 256, 256, 0, stream>>>(x, y16, dst, counts);
    blocksum_kernel  <<<NB1,   256, 0, stream>>>(counts, bsums);
    scanblocks_kernel<<<1,     512, 0, stream>>>(bsums);
    offsets_kernel   <<<NB1,   256, 0, stream>>>(counts, bsums, offsets, cursor);
    fill_kernel      <<<e4blk, 256, 0, stream>>>(src, dst, cursor, csr);
    gather_mlp_kernel<<<NBLK_GM, 256, 0, stream>>>(x, y16, offsets, csr, weights, W1, b1, soutF);
    finalize_kernel  <<<1,      64, 0, stream>>>(soutF, W2, b2, out);
}

// Round 6
// 296.836 us; speedup vs baseline: 2.0936x; 1.3240x over previous
//
#include <hip/hip_runtime.h>
#include <hip/hip_bf16.h>

#define N_NODES 100000
#define N_EDGES 1600000
#define DIM 64
#define NB1 391                 // ceil(N_NODES/256)
#define NGROUPS (N_NODES / 4)   // 25000
#define NBLK_GM 1536            // persistent blocks for gather_mlp
#define CSTRIDE 100096          // per-copy counts stride (ints)
#define E4 (N_EDGES / 4)        // 400000
#define E4BLK 1563              // ceil(E4/256)

// ---------------- workspace layout (int units), total ~24.8 MB ----------------
#define OFF_COUNTS8 0           // 8 * CSTRIDE = 800768
#define OFF_SOUT    800768      // 80
#define OFF_TOT     800848      // 100096
#define OFF_OFFSETS 900944      // 100001
#define OFF_BSUMS   1000960     // 512
#define OFF_CSR     1001472     // 1600000
#define OFF_RANK8   2601472     // 400000 ints (1 byte per edge)
#define OFF_Y16     3001472     // 3200000 ints (bf16 x rows)

__device__ __forceinline__ float blo(unsigned u) { return __uint_as_float(u << 16); }
__device__ __forceinline__ float bhi(unsigned u) { return __uint_as_float(u & 0xffff0000u); }

// ---------------------------------------------------------------------------
// K0: convert x->bf16  +  XCD-private histogram of dst with rank capture.
// Copy = blockIdx&7: with round-robin block->XCD placement, each counts copy
// stays in one XCD's L2 (no cross-XCD line ping-pong). Rank stored 1B/edge.
// ---------------------------------------------------------------------------
__global__ __launch_bounds__(256) void convert_hist_kernel(
    const float* __restrict__ x, unsigned* __restrict__ y,
    const int* __restrict__ dst, int* __restrict__ counts8,
    unsigned* __restrict__ rank8)
{
    int i = blockIdx.x * 256 + threadIdx.x;
    if (i < N_NODES * DIM / 4) {
        float4 v = ((const float4*)x)[i];
        __hip_bfloat162 p0 = __float22bfloat162_rn(make_float2(v.x, v.y));
        __hip_bfloat162 p1 = __float22bfloat162_rn(make_float2(v.z, v.w));
        uint2 o;
        o.x = *reinterpret_cast<unsigned*>(&p0);
        o.y = *reinterpret_cast<unsigned*>(&p1);
        ((uint2*)y)[i] = o;
    }
    if (i < E4) {
        int4 d = ((const int4*)dst)[i];
        int* cnt = counts8 + (blockIdx.x & 7) * CSTRIDE;
        unsigned r0 = (unsigned)atomicAdd(&cnt[d.x], 1);
        unsigned r1 = (unsigned)atomicAdd(&cnt[d.y], 1);
        unsigned r2 = (unsigned)atomicAdd(&cnt[d.z], 1);
        unsigned r3 = (unsigned)atomicAdd(&cnt[d.w], 1);
        rank8[i] = r0 | (r1 << 8) | (r2 << 16) | (r3 << 24);   // ranks < 256
    }
}

// ---------------------------------------------------------------------------
// K1: per-node 8-copy exclusive prefix (in place) + total + per-block sums
// ---------------------------------------------------------------------------
__global__ __launch_bounds__(256) void colsum_blocksum_kernel(
    int* __restrict__ counts8, int* __restrict__ tot, int* __restrict__ bsums)
{
    __shared__ int s[256];
    int t = threadIdx.x;
    int idx = blockIdx.x * 256 + t;
    int run = 0;
    if (idx < N_NODES) {
        #pragma unroll
        for (int k = 0; k < 8; ++k) {
            int v = counts8[k * CSTRIDE + idx];
            counts8[k * CSTRIDE + idx] = run;   // exclusive prefix across copies
            run += v;
        }
        tot[idx] = run;
    }
    s[t] = (idx < N_NODES) ? run : 0;
    __syncthreads();
    for (int d = 128; d > 0; d >>= 1) {
        if (t < d) s[t] += s[t + d];
        __syncthreads();
    }
    if (t == 0) bsums[blockIdx.x] = s[0];
}

// ---------------------------------------------------------------------------
// K2: exclusive scan of the 391 block sums (single block, in place)
// ---------------------------------------------------------------------------
__global__ __launch_bounds__(512) void scanblocks_kernel(int* __restrict__ bsums)
{
    __shared__ int s[512];
    int t = threadIdx.x;
    int v = (t < NB1) ? bsums[t] : 0;
    s[t] = v;
    __syncthreads();
    for (int d = 1; d < 512; d <<= 1) {
        int add = (t >= d) ? s[t - d] : 0;
        __syncthreads();
        s[t] += add;
        __syncthreads();
    }
    if (t < NB1) bsums[t] = (t == 0) ? 0 : s[t - 1];
}

// ---------------------------------------------------------------------------
// K3: per-block scan -> offsets[]; fold node offset into the 8 copy-prefixes
// so counts8[c][d] becomes the absolute CSR base for (copy c, node d).
// ---------------------------------------------------------------------------
__global__ __launch_bounds__(256) void offsets_kernel(
    const int* __restrict__ tot, const int* __restrict__ bsums,
    int* __restrict__ offsets, int* __restrict__ counts8)
{
    __shared__ int s[256];
    int t = threadIdx.x;
    int idx = blockIdx.x * 256 + t;
    int c = (idx < N_NODES) ? tot[idx] : 0;
    s[t] = c;
    __syncthreads();
    for (int d = 1; d < 256; d <<= 1) {
        int add = (t >= d) ? s[t - d] : 0;
        __syncthreads();
        s[t] += add;
        __syncthreads();
    }
    int excl = (t == 0) ? 0 : s[t - 1];
    int off = bsums[blockIdx.x] + excl;
    if (idx < N_NODES) {
        offsets[idx] = off;
        #pragma unroll
        for (int k = 0; k < 8; ++k)
            counts8[k * CSTRIDE + idx] += off;   // absolute base per copy
    }
    if (idx == 0) offsets[N_NODES] = N_EDGES;
}

// ---------------------------------------------------------------------------
// K4: fill CSR — ZERO atomics. pos = base[c][d] + rank[e], c = (e4>>8)&7
// (same copy selection formula as K0's blockIdx&7). Stores fire-and-forget.
// ---------------------------------------------------------------------------
__global__ __launch_bounds__(256) void fill_kernel(
    const int* __restrict__ src, const int* __restrict__ dst,
    const int* __restrict__ counts8, const unsigned* __restrict__ rank8,
    int* __restrict__ csr)
{
    int e4 = blockIdx.x * 256 + threadIdx.x;
    if (e4 < E4) {
        int4 s = ((const int4*)src)[e4];
        int4 d = ((const int4*)dst)[e4];
        unsigned rp = rank8[e4];
        const int* base = counts8 + (((unsigned)e4 >> 8) & 7) * CSTRIDE;
        int p0 = base[d.x] + (int)(rp & 255u);
        int p1 = base[d.y] + (int)((rp >> 8) & 255u);
        int p2 = base[d.z] + (int)((rp >> 16) & 255u);
        int p3 = base[d.w] + (int)((rp >> 24) & 255u);
        csr[p0] = s.x;
        csr[p1] = s.y;
        csr[p2] = s.z;
        csr[p3] = s.w;
    }
}

// ---------------------------------------------------------------------------
// K5: fused bf16 gather + layer-1 matvec + weighted reduction (as R5).
// ---------------------------------------------------------------------------
__global__ __launch_bounds__(256) void gather_mlp_kernel(
    const float* __restrict__ x,
    const unsigned* __restrict__ y16,
    const int* __restrict__ offsets,
    const int* __restrict__ csr,
    const float* __restrict__ weights,
    const float* __restrict__ W1,
    const float* __restrict__ b1,
    float* __restrict__ sout)
{
    __shared__ float W1s[DIM * DIM];      // 16 KB
    __shared__ float vbuf[4][4][DIM];     // 4 KB
    __shared__ float sred[4][DIM];        // 1 KB

    const int tid  = threadIdx.x;
    const int lane = tid & 63;
    const int wave = tid >> 6;
    const int slot = lane >> 3;
    const int h    = lane & 7;

    for (int i = tid; i < DIM * DIM; i += 256) W1s[i] = W1[i];
    __syncthreads();

    const float bias = b1[lane];
    float sacc  = 0.f;
    float swacc = 0.f;

    const uint4* yrows = (const uint4*)y16;

    for (int g = blockIdx.x * 4 + wave; g < NGROUPS; g += NBLK_GM * 4) {
        const int i0 = g * 4;

        int off_l = offsets[i0 + (lane < 5 ? lane : 4)];
        int bg[4], dd[4];
        #pragma unroll
        for (int n = 0; n < 4; ++n) {
            int b = __builtin_amdgcn_readfirstlane(__shfl(off_l, n));
            int e = __builtin_amdgcn_readfirstlane(__shfl(off_l, n + 1));
            bg[n] = b; dd[n] = e - b;
        }

        int idx[4];
        float selfv[4];
        #pragma unroll
        for (int n = 0; n < 4; ++n)
            idx[n] = (lane < dd[n]) ? csr[bg[n] + lane] : 0;
        #pragma unroll
        for (int n = 0; n < 4; ++n)
            selfv[n] = x[(size_t)(i0 + n) * DIM + lane];

        uint4 r[4][3];
        #pragma unroll
        for (int n = 0; n < 4; ++n) {
            #pragma unroll
            for (int c = 0; c < 3; ++c) {
                r[n][c] = make_uint4(0u, 0u, 0u, 0u);
                if (c * 8 < dd[n]) {
                    const int e = c * 8 + slot;
                    const int s = __shfl(idx[n], e);
                    uint4 rr = yrows[(size_t)s * 8 + h];
                    if (e < dd[n]) r[n][c] = rr;
                }
            }
        }

        #pragma unroll
        for (int n = 0; n < 4; ++n) {
            float a0 = 0.f, a1 = 0.f, a2 = 0.f, a3 = 0.f;
            float a4 = 0.f, a5 = 0.f, a6 = 0.f, a7 = 0.f;
            #pragma unroll
            for (int c = 0; c < 3; ++c) {
                uint4 rr = r[n][c];
                a0 += blo(rr.x); a1 += bhi(rr.x);
                a2 += blo(rr.y); a3 += bhi(rr.y);
                a4 += blo(rr.z); a5 += bhi(rr.z);
                a6 += blo(rr.w); a7 += bhi(rr.w);
            }
            if (dd[n] > 24) {
                const int dcap = dd[n] <= 64 ? dd[n] : 64;
                for (int c = 3; c * 8 < dcap; ++c) {
                    const int e = c * 8 + slot;
                    const int s = __shfl(idx[n], e < 64 ? e : 0);
                    if (e < dcap) {
                        uint4 rr = yrows[(size_t)s * 8 + h];
                        a0 += blo(rr.x); a1 += bhi(rr.x);
                        a2 += blo(rr.y); a3 += bhi(rr.y);
                        a4 += blo(rr.z); a5 += bhi(rr.z);
                        a6 += blo(rr.w); a7 += bhi(rr.w);
                    }
                }
                if (dd[n] > 64) {
                    for (int jj = bg[n] + 64; jj < bg[n] + dd[n]; ++jj) {
                        const int s = csr[jj];
                        if (slot == 0) {
                            uint4 rr = yrows[(size_t)s * 8 + h];
                            a0 += blo(rr.x); a1 += bhi(rr.x);
                            a2 += blo(rr.y); a3 += bhi(rr.y);
                            a4 += blo(rr.z); a5 += bhi(rr.z);
                            a6 += blo(rr.w); a7 += bhi(rr.w);
                        }
                    }
                }
            }
            #pragma unroll
            for (int m = 8; m <= 32; m <<= 1) {
                a0 += __shfl_xor(a0, m); a1 += __shfl_xor(a1, m);
                a2 += __shfl_xor(a2, m); a3 += __shfl_xor(a3, m);
                a4 += __shfl_xor(a4, m); a5 += __shfl_xor(a5, m);
                a6 += __shfl_xor(a6, m); a7 += __shfl_xor(a7, m);
            }
            if (lane < 8) {
                *(float4*)&vbuf[wave][n][lane * 8]     = make_float4(a0, a1, a2, a3);
                *(float4*)&vbuf[wave][n][lane * 8 + 4] = make_float4(a4, a5, a6, a7);
            }
            vbuf[wave][n][lane] += selfv[n];
        }

        float a0 = bias, a1 = bias, a2 = bias, a3 = bias;
        #pragma unroll
        for (int k = 0; k < DIM; k += 4) {
            float4 q0 = *(const float4*)&vbuf[wave][0][k];
            float4 q1 = *(const float4*)&vbuf[wave][1][k];
            float4 q2 = *(const float4*)&vbuf[wave][2][k];
            float4 q3 = *(const float4*)&vbuf[wave][3][k];
            float w0 = W1s[(k + 0) * DIM + lane];
            float w1 = W1s[(k + 1) * DIM + lane];
            float w2 = W1s[(k + 2) * DIM + lane];
            float w3 = W1s[(k + 3) * DIM + lane];
            a0 = fmaf(q0.x, w0, a0); a0 = fmaf(q0.y, w1, a0);
            a0 = fmaf(q0.z, w2, a0); a0 = fmaf(q0.w, w3, a0);
            a1 = fmaf(q1.x, w0, a1); a1 = fmaf(q1.y, w1, a1);
            a1 = fmaf(q1.z, w2, a1); a1 = fmaf(q1.w, w3, a1);
            a2 = fmaf(q2.x, w0, a2); a2 = fmaf(q2.y, w1, a2);
            a2 = fmaf(q2.z, w2, a2); a2 = fmaf(q2.w, w3, a2);
            a3 = fmaf(q3.x, w0, a3); a3 = fmaf(q3.y, w1, a3);
            a3 = fmaf(q3.z, w2, a3); a3 = fmaf(q3.w, w3, a3);
        }

        const float wt0 = weights[i0 + 0];
        const float wt1 = weights[i0 + 1];
        const float wt2 = weights[i0 + 2];
        const float wt3 = weights[i0 + 3];
        sacc = fmaf(fmaxf(a0, 0.f), wt0, sacc);
        sacc = fmaf(fmaxf(a1, 0.f), wt1, sacc);
        sacc = fmaf(fmaxf(a2, 0.f), wt2, sacc);
        sacc = fmaf(fmaxf(a3, 0.f), wt3, sacc);
        if (lane == 0) swacc += wt0 + wt1 + wt2 + wt3;
    }

    sred[wave][lane] = sacc;
    __syncthreads();
    if (wave == 0) {
        float t = sred[0][lane] + sred[1][lane] + sred[2][lane] + sred[3][lane];
        atomicAdd(&sout[lane], t);
    }
    if (lane == 0) atomicAdd(&sout[DIM], swacc);
}

// ---------------------------------------------------------------------------
// K6: out = s @ W2 + sw * b2
// ---------------------------------------------------------------------------
__global__ void finalize_kernel(
    const float* __restrict__ sout,
    const float* __restrict__ W2,
    const float* __restrict__ b2,
    float* __restrict__ out)
{
    const int j = threadIdx.x;
    const float sw = sout[DIM];
    float acc = sw * b2[j];
    #pragma unroll
    for (int k = 0; k < DIM; ++k)
        acc = fmaf(sout[k], W2[k * DIM + j], acc);
    out[j] = acc;
}

extern "C" void kernel_launch(void* const* d_in, const int* in_sizes, int n_in,
                              void* d_out, int out_size, void* d_ws, size_t ws_size,
                              hipStream_t stream)
{
    const float* x       = (const float*)d_in[0];
    const int*   ei      = (const int*)d_in[1];
    const float* weights = (const float*)d_in[2];
    const float* W1      = (const float*)d_in[3];
    const float* b1      = (const float*)d_in[4];
    const float* W2      = (const float*)d_in[5];
    const float* b2      = (const float*)d_in[6];
    float* out = (float*)d_out;

    const int* src = ei;
    const int* dst = ei + N_EDGES;

    int*      wsI     = (int*)d_ws;
    int*      counts8 = wsI + OFF_COUNTS8;
    float*    soutF   = (float*)(wsI + OFF_SOUT);
    int*      tot     = wsI + OFF_TOT;
    int*      offsets = wsI + OFF_OFFSETS;
    int*      bsums   = wsI + OFF_BSUMS;
    int*      csr     = wsI + OFF_CSR;
    unsigned* rank8   = (unsigned*)(wsI + OFF_RANK8);
    unsigned* y16     = (unsigned*)(wsI + OFF_Y16);

    // zero counts8 (3.2 MB) + sout in one memset
    hipMemsetAsync(d_ws, 0, (size_t)(OFF_SOUT + 80) * sizeof(int), stream);

    convert_hist_kernel  <<<(N_NODES * DIM / 4 + 255) / 256, 256, 0, stream>>>(x, y16, dst, counts8, rank8);
    colsum_blocksum_kernel<<<NB1,   256, 0, stream>>>(counts8, tot, bsums);
    scanblocks_kernel    <<<1,      512, 0, stream>>>(bsums);
    offsets_kernel       <<<NB1,    256, 0, stream>>>(tot, bsums, offsets, counts8);
    fill_kernel          <<<E4BLK,  256, 0, stream>>>(src, dst, counts8, rank8, csr);
    gather_mlp_kernel    <<<NBLK_GM, 256, 0, stream>>>(x, y16, offsets, csr, weights, W1, b1, soutF);
    finalize_kernel      <<<1,       64, 0, stream>>>(soutF, W2, b2, out);
}